// Round 1
// baseline (444.865 us; speedup 1.0000x reference)
//
#include <hip/hip_runtime.h>
#include <hip/hip_bf16.h>
#include <stdint.h>

#define N_ENT 100000
#define EDIM 128
#define NHEAD 8
#define FDIM 512
#define NB 512
#define SEQ 12
#define CTXL 5
#define LN_EPS 1e-5f

typedef __attribute__((ext_vector_type(8))) short bf16x8;
typedef __attribute__((ext_vector_type(4))) float f32x4;

__device__ __forceinline__ short f2bf(float f) {
  union { float f; uint32_t u; } x; x.f = f;
  uint32_t r = x.u + 0x7FFFu + ((x.u >> 16) & 1u);
  return (short)(r >> 16);
}

// ---------------- gather: build seq [SEQ][NB][EDIM] ----------------
__global__ void gather_kernel(const int* __restrict__ inp,
                              const float* __restrict__ ctxSub,
                              const float* __restrict__ ent,
                              const float* __restrict__ ent_t,
                              const float* __restrict__ rel,
                              const float* __restrict__ rel_inv,
                              const float* __restrict__ ctx,
                              float* __restrict__ x) {
  int b = blockIdx.x;
  int e = threadIdx.x;  // 128
  int i0 = inp[0 * NB + b], i1 = inp[1 * NB + b], i2 = inp[2 * NB + b];
  x[(0 * NB + b) * EDIM + e] = ent[i0 * EDIM + e];
  x[(1 * NB + b) * EDIM + e] = ent_t[i0 * EDIM + e];
  x[(2 * NB + b) * EDIM + e] = rel[i1 * EDIM + e];
  x[(3 * NB + b) * EDIM + e] = rel_inv[i1 * EDIM + e];
  x[(4 * NB + b) * EDIM + e] = ent[i2 * EDIM + e];
  x[(5 * NB + b) * EDIM + e] = ent_t[i2 * EDIM + e];
  for (int j = 0; j < CTXL; ++j) {
    int c = inp[(3 + j) * NB + b];
    x[((6 + j) * NB + b) * EDIM + e] = ctx[c * EDIM + e];
  }
  x[(11 * NB + b) * EDIM + e] = ctxSub[b * EDIM + e];
}

// ---------------- LN helper: wave w handles tokens w, w+4, w+8 -------------
__device__ __forceinline__ void ln_block(float (*src)[EDIM], float (*dst)[EDIM],
                                         const float* __restrict__ g,
                                         const float* __restrict__ be, int tid) {
  int wave = tid >> 6, lane = tid & 63;
  for (int t = wave; t < SEQ; t += 4) {
    float v0 = src[t][lane * 2], v1 = src[t][lane * 2 + 1];
    float sum = v0 + v1, sq = v0 * v0 + v1 * v1;
#pragma unroll
    for (int off = 32; off; off >>= 1) {
      sum += __shfl_xor(sum, off);
      sq += __shfl_xor(sq, off);
    }
    float mu = sum * (1.0f / 128.0f);
    float var = sq * (1.0f / 128.0f) - mu * mu;
    float rs = rsqrtf(var + LN_EPS);
    dst[t][lane * 2] = (v0 - mu) * rs * g[lane * 2] + be[lane * 2];
    dst[t][lane * 2 + 1] = (v1 - mu) * rs * g[lane * 2 + 1] + be[lane * 2 + 1];
  }
}

// ---------------- one encoder layer, one block per batch element -----------
__global__ __launch_bounds__(256) void encoder_layer(
    float* __restrict__ x, const float* __restrict__ Wqkv,
    const float* __restrict__ bqkv, const float* __restrict__ Wo,
    const float* __restrict__ bo, const float* __restrict__ W1,
    const float* __restrict__ b1, const float* __restrict__ W2,
    const float* __restrict__ b2, const float* __restrict__ g1,
    const float* __restrict__ be1, const float* __restrict__ g2,
    const float* __restrict__ be2) {
  __shared__ float xs[SEQ][EDIM];        // 6 KB
  __shared__ float qkvs[SEQ][3 * EDIM];  // 18 KB
  __shared__ float atto[SEQ][EDIM];      // 6 KB
  __shared__ float h1s[SEQ][FDIM];       // 24 KB
  __shared__ float rbuf[SEQ][EDIM];      // 6 KB
  int b = blockIdx.x;
  int tid = threadIdx.x;

  for (int i = tid; i < SEQ * EDIM; i += 256) {
    int t = i / EDIM, e = i % EDIM;
    xs[t][e] = x[(t * NB + b) * EDIM + e];
  }
  __syncthreads();

  // qkv = x @ Wqkv.T + bqkv
  for (int o = tid; o < 3 * EDIM; o += 256) {
    const float* wr = Wqkv + o * EDIM;
    float bias = bqkv[o];
    float acc[SEQ];
#pragma unroll
    for (int t = 0; t < SEQ; ++t) acc[t] = bias;
    for (int e = 0; e < EDIM; e += 4) {
      float4 w = *(const float4*)(wr + e);
#pragma unroll
      for (int t = 0; t < SEQ; ++t)
        acc[t] += w.x * xs[t][e] + w.y * xs[t][e + 1] + w.z * xs[t][e + 2] +
                  w.w * xs[t][e + 3];
    }
#pragma unroll
    for (int t = 0; t < SEQ; ++t) qkvs[t][o] = acc[t];
  }
  __syncthreads();

  // attention: 96 threads, one (head, query-token) each; Dh=16, scale=0.25
  if (tid < NHEAD * SEQ) {
    int h = tid % NHEAD, tq = tid / NHEAD;
    const float scale = 0.25f;
    float s[SEQ];
    float mx = -1e30f;
#pragma unroll
    for (int tk = 0; tk < SEQ; ++tk) {
      float d = 0.f;
#pragma unroll
      for (int dd = 0; dd < 16; ++dd)
        d += qkvs[tq][h * 16 + dd] * qkvs[tk][EDIM + h * 16 + dd];
      s[tk] = d * scale;
      mx = fmaxf(mx, s[tk]);
    }
    float sum = 0.f;
#pragma unroll
    for (int tk = 0; tk < SEQ; ++tk) {
      s[tk] = __expf(s[tk] - mx);
      sum += s[tk];
    }
    float inv = 1.0f / sum;
#pragma unroll
    for (int dd = 0; dd < 16; ++dd) {
      float o = 0.f;
#pragma unroll
      for (int tk = 0; tk < SEQ; ++tk) o += s[tk] * qkvs[tk][2 * EDIM + h * 16 + dd];
      atto[tq][h * 16 + dd] = o * inv;
    }
  }
  __syncthreads();

  // out-proj + residual
  {
    int e = tid % EDIM, half = tid / EDIM;
    const float* wr = Wo + e * EDIM;
    float acc[6];
#pragma unroll
    for (int t = 0; t < 6; ++t) acc[t] = bo[e];
    for (int i = 0; i < EDIM; i += 4) {
      float4 w = *(const float4*)(wr + i);
#pragma unroll
      for (int t = 0; t < 6; ++t) {
        int tt = half * 6 + t;
        acc[t] += w.x * atto[tt][i] + w.y * atto[tt][i + 1] +
                  w.z * atto[tt][i + 2] + w.w * atto[tt][i + 3];
      }
    }
#pragma unroll
    for (int t = 0; t < 6; ++t) {
      int tt = half * 6 + t;
      rbuf[tt][e] = xs[tt][e] + acc[t];
    }
  }
  __syncthreads();
  ln_block(rbuf, xs, g1, be1, tid);
  __syncthreads();

  // FFN1 (relu)
  for (int f = tid; f < FDIM; f += 256) {
    const float* wr = W1 + f * EDIM;
    float bias = b1[f];
    float acc[SEQ];
#pragma unroll
    for (int t = 0; t < SEQ; ++t) acc[t] = bias;
    for (int e = 0; e < EDIM; e += 4) {
      float4 w = *(const float4*)(wr + e);
#pragma unroll
      for (int t = 0; t < SEQ; ++t)
        acc[t] += w.x * xs[t][e] + w.y * xs[t][e + 1] + w.z * xs[t][e + 2] +
                  w.w * xs[t][e + 3];
    }
#pragma unroll
    for (int t = 0; t < SEQ; ++t) h1s[t][f] = fmaxf(acc[t], 0.0f);
  }
  __syncthreads();

  // FFN2 + residual
  {
    int e = tid % EDIM, half = tid / EDIM;
    const float* wr = W2 + e * FDIM;
    float acc[6];
#pragma unroll
    for (int t = 0; t < 6; ++t) acc[t] = b2[e];
    for (int f = 0; f < FDIM; f += 4) {
      float4 w = *(const float4*)(wr + f);
#pragma unroll
      for (int t = 0; t < 6; ++t) {
        int tt = half * 6 + t;
        acc[t] += w.x * h1s[tt][f] + w.y * h1s[tt][f + 1] +
                  w.z * h1s[tt][f + 2] + w.w * h1s[tt][f + 3];
      }
    }
#pragma unroll
    for (int t = 0; t < 6; ++t) {
      int tt = half * 6 + t;
      rbuf[tt][e] = xs[tt][e] + acc[t];
    }
  }
  __syncthreads();
  ln_block(rbuf, xs, g2, be2, tid);
  __syncthreads();

  for (int i = tid; i < SEQ * EDIM; i += 256) {
    int t = i / EDIM, e = i % EDIM;
    x[(t * NB + b) * EDIM + e] = xs[t][e];
  }
}

// --------- prep: A_bf16[512][256] = concat(sh*nrel, st*ninv); history ------
__global__ void prep_kernel(const float* __restrict__ x,
                            const int* __restrict__ nextCheckin,
                            const float* __restrict__ rel,
                            const float* __restrict__ rel_inv,
                            short* __restrict__ Abf,
                            float* __restrict__ hist) {
  int b = blockIdx.x;
  int e = threadIdx.x;  // 128
  int r = nextCheckin[1 * NB + b];
  float a0 = x[(0 * NB + b) * EDIM + e] * rel[r * EDIM + e];
  float a1 = x[(1 * NB + b) * EDIM + e] * rel_inv[r * EDIM + e];
  Abf[b * 256 + e] = f2bf(a0);
  Abf[b * 256 + 128 + e] = f2bf(a1);
  hist[b * EDIM + e] = x[(11 * NB + b) * EDIM + e];
}

// ---------------- scores: bf16 MFMA GEMM, M=512 N=100000 K=256 -------------
// grid: 12504 1D blocks; XCD-aware remap so the 8 M-blocks of an N-panel run
// consecutively on the SAME XCD (private L2 B-panel reuse).
#define NTILES 1563
__global__ __launch_bounds__(256) void score_kernel(
    const short* __restrict__ Abf, const float* __restrict__ ent,
    const float* __restrict__ ent_t, float* __restrict__ out) {
  int i = blockIdx.x;
  int xcd = i % 8, j = i / 8;
  int w = xcd * NTILES + j;  // work index: ntile-major per XCD
  int ntile = w / 8;
  int mtile = w % 8;

  int wave = threadIdx.x >> 6;
  int lane = threadIdx.x & 63;
  int m0 = mtile * 64;
  int n0 = ntile * 64 + wave * 16;
  int nrow = n0 + (lane & 15);
  int krow = (lane >> 4) * 8;
  bool nvalid = (nrow < N_ENT);

  f32x4 acc[4];
#pragma unroll
  for (int mi = 0; mi < 4; ++mi)
#pragma unroll
    for (int r = 0; r < 4; ++r) acc[mi][r] = 0.0f;

#pragma unroll
  for (int kk = 0; kk < 8; ++kk) {
    int k0 = kk * 32 + krow;  // 8 contiguous k's, never straddles the 128 split
    float tmp[8];
    if (nvalid) {
      const float* src = (k0 < 128) ? (ent + (size_t)nrow * 128 + k0)
                                    : (ent_t + (size_t)nrow * 128 + (k0 - 128));
      float4 f0 = *(const float4*)(src);
      float4 f1 = *(const float4*)(src + 4);
      tmp[0] = f0.x; tmp[1] = f0.y; tmp[2] = f0.z; tmp[3] = f0.w;
      tmp[4] = f1.x; tmp[5] = f1.y; tmp[6] = f1.z; tmp[7] = f1.w;
    } else {
#pragma unroll
      for (int q = 0; q < 8; ++q) tmp[q] = 0.0f;
    }
    bf16x8 bfrag;
#pragma unroll
    for (int q = 0; q < 8; ++q) bfrag[q] = f2bf(tmp[q]);

#pragma unroll
    for (int mi = 0; mi < 4; ++mi) {
      bf16x8 afrag =
          *(const bf16x8*)(Abf + (size_t)(m0 + mi * 16 + (lane & 15)) * 256 + k0);
      acc[mi] = __builtin_amdgcn_mfma_f32_16x16x32_bf16(afrag, bfrag, acc[mi], 0, 0, 0);
    }
  }

  int col = n0 + (lane & 15);
  if (col < N_ENT) {
#pragma unroll
    for (int mi = 0; mi < 4; ++mi) {
      int mrow = m0 + mi * 16 + (lane >> 4) * 4;
#pragma unroll
      for (int r = 0; r < 4; ++r) {
        float v = acc[mi][r] * 0.5f;
        v = fminf(fmaxf(v, -20.0f), 20.0f);
        out[(size_t)(mrow + r) * N_ENT + col] = v;
      }
    }
  }
}

extern "C" void kernel_launch(void* const* d_in, const int* in_sizes, int n_in,
                              void* d_out, int out_size, void* d_ws,
                              size_t ws_size, hipStream_t stream) {
  const int* inp = (const int*)d_in[0];
  const int* nextCheckin = (const int*)d_in[1];
  const float* ctxSub = (const float*)d_in[2];
  const float* ent = (const float*)d_in[3];
  const float* ent_t = (const float*)d_in[4];
  const float* rel = (const float*)d_in[5];
  const float* rel_inv = (const float*)d_in[6];
  const float* ctx = (const float*)d_in[7];
  const float* Wqkv = (const float*)d_in[8];
  const float* bqkv = (const float*)d_in[9];
  const float* Wo = (const float*)d_in[10];
  const float* bo = (const float*)d_in[11];
  const float* W1 = (const float*)d_in[12];
  const float* b1 = (const float*)d_in[13];
  const float* W2 = (const float*)d_in[14];
  const float* b2 = (const float*)d_in[15];
  const float* g1 = (const float*)d_in[16];
  const float* be1 = (const float*)d_in[17];
  const float* g2 = (const float*)d_in[18];
  const float* be2 = (const float*)d_in[19];
  float* out = (float*)d_out;

  float* x = (float*)d_ws;                                      // 3 MB
  short* Abf = (short*)((char*)d_ws + (size_t)SEQ * NB * EDIM * 4);  // 256 KB

  gather_kernel<<<NB, EDIM, 0, stream>>>(inp, ctxSub, ent, ent_t, rel, rel_inv,
                                         ctx, x);
  for (int l = 0; l < 2; ++l) {
    encoder_layer<<<NB, 256, 0, stream>>>(
        x, Wqkv + l * 384 * 128, bqkv + l * 384, Wo + l * 128 * 128,
        bo + l * 128, W1 + l * 512 * 128, b1 + l * 512, W2 + l * 128 * 512,
        b2 + l * 128, g1 + l * 128, be1 + l * 128, g2 + l * 128, be2 + l * 128);
  }
  prep_kernel<<<NB, EDIM, 0, stream>>>(x, nextCheckin, rel, rel_inv, Abf,
                                       out + (size_t)NB * N_ENT);
  score_kernel<<<8 * NTILES, 256, 0, stream>>>(Abf, ent, ent_t, out);
}

// Round 2
// 267.169 us; speedup vs baseline: 1.6651x; 1.6651x over previous
//
#include <hip/hip_runtime.h>
#include <hip/hip_bf16.h>
#include <stdint.h>

#define N_ENT 100000
#define EDIM 128
#define NHEAD 8
#define FDIM 512
#define NB 512
#define SEQ 12
#define CTXL 5
#define LN_EPS 1e-5f

typedef __attribute__((ext_vector_type(8))) short bf16x8;
typedef __attribute__((ext_vector_type(4))) float f32x4;

__device__ __forceinline__ short f2bf(float f) {
  union { float f; uint32_t u; } x; x.f = f;
  uint32_t r = x.u + 0x7FFFu + ((x.u >> 16) & 1u);
  return (short)(r >> 16);
}

// ---------------- gather: build seq [SEQ][NB][EDIM] ----------------
__global__ void gather_kernel(const int* __restrict__ inp,
                              const float* __restrict__ ctxSub,
                              const float* __restrict__ ent,
                              const float* __restrict__ ent_t,
                              const float* __restrict__ rel,
                              const float* __restrict__ rel_inv,
                              const float* __restrict__ ctx,
                              float* __restrict__ x) {
  int b = blockIdx.x;
  int e = threadIdx.x;  // 128
  int i0 = inp[0 * NB + b], i1 = inp[1 * NB + b], i2 = inp[2 * NB + b];
  x[(0 * NB + b) * EDIM + e] = ent[i0 * EDIM + e];
  x[(1 * NB + b) * EDIM + e] = ent_t[i0 * EDIM + e];
  x[(2 * NB + b) * EDIM + e] = rel[i1 * EDIM + e];
  x[(3 * NB + b) * EDIM + e] = rel_inv[i1 * EDIM + e];
  x[(4 * NB + b) * EDIM + e] = ent[i2 * EDIM + e];
  x[(5 * NB + b) * EDIM + e] = ent_t[i2 * EDIM + e];
  for (int j = 0; j < CTXL; ++j) {
    int c = inp[(3 + j) * NB + b];
    x[((6 + j) * NB + b) * EDIM + e] = ctx[c * EDIM + e];
  }
  x[(11 * NB + b) * EDIM + e] = ctxSub[b * EDIM + e];
}

// ---------------- LN helper: wave w handles tokens w, w+4, w+8 -------------
__device__ __forceinline__ void ln_block(float (*src)[EDIM], float (*dst)[EDIM],
                                         const float* __restrict__ g,
                                         const float* __restrict__ be, int tid) {
  int wave = tid >> 6, lane = tid & 63;
  for (int t = wave; t < SEQ; t += 4) {
    float v0 = src[t][lane * 2], v1 = src[t][lane * 2 + 1];
    float sum = v0 + v1, sq = v0 * v0 + v1 * v1;
#pragma unroll
    for (int off = 32; off; off >>= 1) {
      sum += __shfl_xor(sum, off);
      sq += __shfl_xor(sq, off);
    }
    float mu = sum * (1.0f / 128.0f);
    float var = sq * (1.0f / 128.0f) - mu * mu;
    float rs = rsqrtf(var + LN_EPS);
    dst[t][lane * 2] = (v0 - mu) * rs * g[lane * 2] + be[lane * 2];
    dst[t][lane * 2 + 1] = (v1 - mu) * rs * g[lane * 2 + 1] + be[lane * 2 + 1];
  }
}

// ---------------- one encoder layer, one block per batch element -----------
__global__ __launch_bounds__(256) void encoder_layer(
    float* __restrict__ x, const float* __restrict__ Wqkv,
    const float* __restrict__ bqkv, const float* __restrict__ Wo,
    const float* __restrict__ bo, const float* __restrict__ W1,
    const float* __restrict__ b1, const float* __restrict__ W2,
    const float* __restrict__ b2, const float* __restrict__ g1,
    const float* __restrict__ be1, const float* __restrict__ g2,
    const float* __restrict__ be2) {
  __shared__ float xs[SEQ][EDIM];        // 6 KB
  __shared__ float qkvs[SEQ][3 * EDIM];  // 18 KB
  __shared__ float atto[SEQ][EDIM];      // 6 KB
  __shared__ float h1s[SEQ][FDIM];       // 24 KB
  __shared__ float rbuf[SEQ][EDIM];      // 6 KB
  int b = blockIdx.x;
  int tid = threadIdx.x;

  for (int i = tid; i < SEQ * EDIM; i += 256) {
    int t = i / EDIM, e = i % EDIM;
    xs[t][e] = x[(t * NB + b) * EDIM + e];
  }
  __syncthreads();

  // qkv = x @ Wqkv.T + bqkv
  for (int o = tid; o < 3 * EDIM; o += 256) {
    const float* wr = Wqkv + o * EDIM;
    float bias = bqkv[o];
    float acc[SEQ];
#pragma unroll
    for (int t = 0; t < SEQ; ++t) acc[t] = bias;
    for (int e = 0; e < EDIM; e += 4) {
      float4 w = *(const float4*)(wr + e);
#pragma unroll
      for (int t = 0; t < SEQ; ++t)
        acc[t] += w.x * xs[t][e] + w.y * xs[t][e + 1] + w.z * xs[t][e + 2] +
                  w.w * xs[t][e + 3];
    }
#pragma unroll
    for (int t = 0; t < SEQ; ++t) qkvs[t][o] = acc[t];
  }
  __syncthreads();

  // attention: 96 threads, one (head, query-token) each; Dh=16, scale=0.25
  if (tid < NHEAD * SEQ) {
    int h = tid % NHEAD, tq = tid / NHEAD;
    const float scale = 0.25f;
    float s[SEQ];
    float mx = -1e30f;
#pragma unroll
    for (int tk = 0; tk < SEQ; ++tk) {
      float d = 0.f;
#pragma unroll
      for (int dd = 0; dd < 16; ++dd)
        d += qkvs[tq][h * 16 + dd] * qkvs[tk][EDIM + h * 16 + dd];
      s[tk] = d * scale;
      mx = fmaxf(mx, s[tk]);
    }
    float sum = 0.f;
#pragma unroll
    for (int tk = 0; tk < SEQ; ++tk) {
      s[tk] = __expf(s[tk] - mx);
      sum += s[tk];
    }
    float inv = 1.0f / sum;
#pragma unroll
    for (int dd = 0; dd < 16; ++dd) {
      float o = 0.f;
#pragma unroll
      for (int tk = 0; tk < SEQ; ++tk) o += s[tk] * qkvs[tk][2 * EDIM + h * 16 + dd];
      atto[tq][h * 16 + dd] = o * inv;
    }
  }
  __syncthreads();

  // out-proj + residual
  {
    int e = tid % EDIM, half = tid / EDIM;
    const float* wr = Wo + e * EDIM;
    float acc[6];
#pragma unroll
    for (int t = 0; t < 6; ++t) acc[t] = bo[e];
    for (int i = 0; i < EDIM; i += 4) {
      float4 w = *(const float4*)(wr + i);
#pragma unroll
      for (int t = 0; t < 6; ++t) {
        int tt = half * 6 + t;
        acc[t] += w.x * atto[tt][i] + w.y * atto[tt][i + 1] +
                  w.z * atto[tt][i + 2] + w.w * atto[tt][i + 3];
      }
    }
#pragma unroll
    for (int t = 0; t < 6; ++t) {
      int tt = half * 6 + t;
      rbuf[tt][e] = xs[tt][e] + acc[t];
    }
  }
  __syncthreads();
  ln_block(rbuf, xs, g1, be1, tid);
  __syncthreads();

  // FFN1 (relu)
  for (int f = tid; f < FDIM; f += 256) {
    const float* wr = W1 + f * EDIM;
    float bias = b1[f];
    float acc[SEQ];
#pragma unroll
    for (int t = 0; t < SEQ; ++t) acc[t] = bias;
    for (int e = 0; e < EDIM; e += 4) {
      float4 w = *(const float4*)(wr + e);
#pragma unroll
      for (int t = 0; t < SEQ; ++t)
        acc[t] += w.x * xs[t][e] + w.y * xs[t][e + 1] + w.z * xs[t][e + 2] +
                  w.w * xs[t][e + 3];
    }
#pragma unroll
    for (int t = 0; t < SEQ; ++t) h1s[t][f] = fmaxf(acc[t], 0.0f);
  }
  __syncthreads();

  // FFN2 + residual
  {
    int e = tid % EDIM, half = tid / EDIM;
    const float* wr = W2 + e * FDIM;
    float acc[6];
#pragma unroll
    for (int t = 0; t < 6; ++t) acc[t] = b2[e];
    for (int f = 0; f < FDIM; f += 4) {
      float4 w = *(const float4*)(wr + f);
#pragma unroll
      for (int t = 0; t < 6; ++t) {
        int tt = half * 6 + t;
        acc[t] += w.x * h1s[tt][f] + w.y * h1s[tt][f + 1] +
                  w.z * h1s[tt][f + 2] + w.w * h1s[tt][f + 3];
      }
    }
#pragma unroll
    for (int t = 0; t < 6; ++t) {
      int tt = half * 6 + t;
      rbuf[tt][e] = xs[tt][e] + acc[t];
    }
  }
  __syncthreads();
  ln_block(rbuf, xs, g2, be2, tid);
  __syncthreads();

  for (int i = tid; i < SEQ * EDIM; i += 256) {
    int t = i / EDIM, e = i % EDIM;
    x[(t * NB + b) * EDIM + e] = xs[t][e];
  }
}

// --------- prep: A_bf16[512][256] (PRE-SWIZZLED, 16B-chunk ^= row&7) -------
// Abfs[m][ (c ^ (m&7))*8 + j ] = A[m][c*8+j]   (c = k/8, j = k%8)
__global__ void prep_kernel(const float* __restrict__ x,
                            const int* __restrict__ nextCheckin,
                            const float* __restrict__ rel,
                            const float* __restrict__ rel_inv,
                            short* __restrict__ Abfs,
                            float* __restrict__ hist) {
  int b = blockIdx.x;
  int e = threadIdx.x;  // 128
  int r = nextCheckin[1 * NB + b];
  float a0 = x[(0 * NB + b) * EDIM + e] * rel[r * EDIM + e];
  float a1 = x[(1 * NB + b) * EDIM + e] * rel_inv[r * EDIM + e];
  int c = e >> 3, j = e & 7, s = b & 7;
  Abfs[b * 256 + ((c ^ s) << 3) + j] = f2bf(a0);
  Abfs[b * 256 + 128 + ((c ^ s) << 3) + j] = f2bf(a1);
  hist[b * EDIM + e] = x[(11 * NB + b) * EDIM + e];
}

// ---------------- scores: bf16 MFMA GEMM, M=512 N=100000 K=256 -------------
// One block per 64-col N-strip (1563 blocks). B staged once fp32->bf16 into
// swizzled LDS; A streamed through LDS in 8 chunks of 64 rows via
// global_load_lds width=16 from the pre-swizzled Abfs. Each ent/ent_t element
// fetched from HBM exactly once.
__global__ __launch_bounds__(256) void score_kernel(
    const short* __restrict__ Abfs, const float* __restrict__ ent,
    const float* __restrict__ ent_t, float* __restrict__ out) {
  __shared__ char lds[65536];
  char* Asb = lds;           // 32 KB: A chunk [64][256] bf16, swizzled
  char* Bsb = lds + 32768;   // 32 KB: B strip [64][256] bf16, swizzled

  int tid = threadIdx.x;
  int wave = tid >> 6;
  int lane = tid & 63;
  int nbase = blockIdx.x * 64;

  // ---- stage B strip: 64 rows x 256 k fp32 -> bf16, swizzled ds_write ----
#pragma unroll
  for (int i = 0; i < 16; ++i) {
    int flat = i * 256 + tid;  // 0..4095 float4 slots
    int row = flat >> 6;       // 0..63
    int c4 = flat & 63;        // float4 index within row (k = c4*4)
    int n = nbase + row;
    float4 v = make_float4(0.f, 0.f, 0.f, 0.f);
    if (n < N_ENT) {
      const float* src = (c4 < 32) ? ent + (size_t)n * 128 + c4 * 4
                                   : ent_t + (size_t)n * 128 + (c4 - 32) * 4;
      v = *(const float4*)src;
    }
    short4 bb;
    bb.x = f2bf(v.x); bb.y = f2bf(v.y); bb.z = f2bf(v.z); bb.w = f2bf(v.w);
    int chunk = c4 >> 1, half = c4 & 1;
    *(short4*)(Bsb + row * 512 + ((chunk ^ (row & 7)) << 4) + half * 8) = bb;
  }

  const char* gA = (const char*)Abfs;
  int q = lane >> 4;   // 0..3 (k-quarter)
  int lr = lane & 15;
  int rb = wave * 16 + lr;               // B lds row for this wave
  int col = nbase + wave * 16 + lr;      // output column

  f32x4 acc[4];

  for (int mc = 0; mc < 8; ++mc) {
    __syncthreads();  // previous chunk's LDS reads done / B writes visible
    // ---- stage A chunk (64 rows = 32 KB), 8 KB per wave ----
#pragma unroll
    for (int it = 0; it < 8; ++it) {
      int off = wave * 8192 + it * 1024;
      __builtin_amdgcn_global_load_lds(
          (const __attribute__((address_space(1))) uint32_t*)(gA + (size_t)mc * 32768 + off + lane * 16),
          (__attribute__((address_space(3))) uint32_t*)(Asb + off), 16, 0, 0);
    }
    __syncthreads();  // staging complete (vmcnt drained by barrier)

#pragma unroll
    for (int mi = 0; mi < 4; ++mi)
#pragma unroll
      for (int r = 0; r < 4; ++r) acc[mi][r] = 0.0f;

#pragma unroll
    for (int ks = 0; ks < 8; ++ks) {
      int chunk = (ks << 2) | q;
      bf16x8 bfrag = *(const bf16x8*)(Bsb + rb * 512 + ((chunk ^ (rb & 7)) << 4));
#pragma unroll
      for (int mi = 0; mi < 4; ++mi) {
        int ra = mi * 16 + lr;
        bf16x8 afrag = *(const bf16x8*)(Asb + ra * 512 + ((chunk ^ (ra & 7)) << 4));
        acc[mi] = __builtin_amdgcn_mfma_f32_16x16x32_bf16(afrag, bfrag, acc[mi], 0, 0, 0);
      }
    }

    if (col < N_ENT) {
#pragma unroll
      for (int mi = 0; mi < 4; ++mi) {
        int mrow = mc * 64 + mi * 16 + q * 4;
#pragma unroll
        for (int r = 0; r < 4; ++r) {
          float v = acc[mi][r] * 0.5f;
          v = fminf(fmaxf(v, -20.0f), 20.0f);
          out[(size_t)(mrow + r) * N_ENT + col] = v;
        }
      }
    }
  }
}

extern "C" void kernel_launch(void* const* d_in, const int* in_sizes, int n_in,
                              void* d_out, int out_size, void* d_ws,
                              size_t ws_size, hipStream_t stream) {
  const int* inp = (const int*)d_in[0];
  const int* nextCheckin = (const int*)d_in[1];
  const float* ctxSub = (const float*)d_in[2];
  const float* ent = (const float*)d_in[3];
  const float* ent_t = (const float*)d_in[4];
  const float* rel = (const float*)d_in[5];
  const float* rel_inv = (const float*)d_in[6];
  const float* ctx = (const float*)d_in[7];
  const float* Wqkv = (const float*)d_in[8];
  const float* bqkv = (const float*)d_in[9];
  const float* Wo = (const float*)d_in[10];
  const float* bo = (const float*)d_in[11];
  const float* W1 = (const float*)d_in[12];
  const float* b1 = (const float*)d_in[13];
  const float* W2 = (const float*)d_in[14];
  const float* b2 = (const float*)d_in[15];
  const float* g1 = (const float*)d_in[16];
  const float* be1 = (const float*)d_in[17];
  const float* g2 = (const float*)d_in[18];
  const float* be2 = (const float*)d_in[19];
  float* out = (float*)d_out;

  float* x = (float*)d_ws;                                           // 3 MB
  short* Abfs = (short*)((char*)d_ws + (size_t)SEQ * NB * EDIM * 4); // 256 KB

  gather_kernel<<<NB, EDIM, 0, stream>>>(inp, ctxSub, ent, ent_t, rel, rel_inv,
                                         ctx, x);
  for (int l = 0; l < 2; ++l) {
    encoder_layer<<<NB, 256, 0, stream>>>(
        x, Wqkv + l * 384 * 128, bqkv + l * 384, Wo + l * 128 * 128,
        bo + l * 128, W1 + l * 512 * 128, b1 + l * 512, W2 + l * 128 * 512,
        b2 + l * 128, g1 + l * 128, be1 + l * 128, g2 + l * 128, be2 + l * 128);
  }
  prep_kernel<<<NB, EDIM, 0, stream>>>(x, nextCheckin, rel, rel_inv, Abfs,
                                       out + (size_t)NB * N_ENT);
  score_kernel<<<1563, 256, 0, stream>>>(Abfs, ent, ent_t, out);
}